// Round 1
// baseline (905.870 us; speedup 1.0000x reference)
//
#include <hip/hip_runtime.h>

#define HW 512

// ---------------------------------------------------------------------------
// Grouped directional conv, one scale per instantiation.
// Filters are identical across the 3 color groups, so we stage only the
// first NDIR filters. Correlation (no flip), zero padding, 'same'.
// Each block: 32x32 output pixels of one (b,c) plane, all NDIR directions.
// Each thread: 4 consecutive x pixels, all NDIR accumulators in registers.
// ---------------------------------------------------------------------------
template<int K, int NDIR, int SUB0>
__global__ __launch_bounds__(256)
void conv_kernel(const float* __restrict__ img, const float* __restrict__ filt,
                 float* __restrict__ out)
{
    constexpr int R  = K / 2;
    constexpr int TW = 32 + 2 * R;            // tile width incl. halo
    constexpr int TH = 32 + 2 * R;            // tile height incl. halo
    constexpr int SP = (TW + 3) & ~3;         // LDS row stride (x4 floats -> 16B aligned)
    constexpr int KP = (K + 3) & ~3;          // padded filter row

    __shared__ float s_in[TH * SP];
    __shared__ float s_f[NDIR * K * KP];

    const int tid   = threadIdx.x;
    const int bx    = blockIdx.x, by = blockIdx.y;
    const int plane = blockIdx.z;             // b*3 + c
    const int b     = plane / 3, c = plane % 3;

    const float* __restrict__ src = img + (size_t)plane * HW * HW;
    const int ox = bx * 32 - R;
    const int oy = by * 32 - R;

    // ---- stage input tile (zero-padded OOB) ----
    for (int idx = tid; idx < TH * SP; idx += 256) {
        const int r = idx / SP, col = idx % SP;
        const int gy = oy + r, gx = ox + col;
        float v = 0.f;
        if (gy >= 0 && gy < HW && gx >= 0 && gx < HW && col < TW)
            v = src[gy * HW + gx];
        s_in[idx] = v;
    }
    // ---- stage filters with row padding to KP ----
    for (int idx = tid; idx < NDIR * K * KP; idx += 256) {
        const int d   = idx / (K * KP);
        const int rem = idx - d * K * KP;
        const int r   = rem / KP, col = rem % KP;
        float v = 0.f;
        if (col < K) v = filt[(d * K + r) * K + col];
        s_f[idx] = v;
    }
    __syncthreads();

    const int tx = (tid & 7) * 4;             // 0,4,...,28
    const int ty = tid >> 3;                  // 0..31

    float acc[NDIR][4];
    #pragma unroll
    for (int d = 0; d < NDIR; ++d) {
        acc[d][0] = 0.f; acc[d][1] = 0.f; acc[d][2] = 0.f; acc[d][3] = 0.f;
    }

    constexpr int WREGS = (K + 3 + 3) & ~3;   // register window, x4 floats

    for (int dy = 0; dy < K; ++dy) {
        // register window of the input row this thread needs (16B-aligned LDS reads)
        float w[WREGS];
        const float4* __restrict__ rowp =
            (const float4*)&s_in[(ty + dy) * SP + tx];
        #pragma unroll
        for (int i = 0; i < WREGS / 4; ++i) {
            const float4 v = rowp[i];
            w[4*i+0] = v.x; w[4*i+1] = v.y; w[4*i+2] = v.z; w[4*i+3] = v.w;
        }
        #pragma unroll
        for (int d = 0; d < NDIR; ++d) {
            float fr[KP];
            const float4* __restrict__ fp =
                (const float4*)&s_f[(d * K + dy) * KP];
            #pragma unroll
            for (int i = 0; i < KP / 4; ++i) {
                const float4 v = fp[i];
                fr[4*i+0] = v.x; fr[4*i+1] = v.y; fr[4*i+2] = v.z; fr[4*i+3] = v.w;
            }
            #pragma unroll
            for (int dx = 0; dx < K; ++dx) {
                #pragma unroll
                for (int i = 0; i < 4; ++i)
                    acc[d][i] = fmaf(fr[dx], w[dx + i], acc[d][i]);
            }
        }
    }

    const int gy = by * 32 + ty, gx = bx * 32 + tx;
    #pragma unroll
    for (int d = 0; d < NDIR; ++d) {
        const size_t o =
            ((size_t)(b * 87 + c * 29 + SUB0 + d) * HW + gy) * HW + gx;
        *(float4*)&out[o] = make_float4(acc[d][0], acc[d][1], acc[d][2], acc[d][3]);
    }
}

// ---------------------------------------------------------------------------
// Low channel: 4x4 avg-pool then 4x bilinear upsample (half-pixel centers,
// edge clamp == jax renormalized triangle kernel). Fused via LDS pooled tile
// with 1-element clamped halo; each block emits a 128x128 output tile.
// ---------------------------------------------------------------------------
__global__ __launch_bounds__(256)
void low_kernel(const float* __restrict__ img, float* __restrict__ out)
{
    __shared__ float s_p[34 * 35];
    const int tid   = threadIdx.x;
    const int bx    = blockIdx.x, by = blockIdx.y;
    const int plane = blockIdx.z;
    const int b     = plane / 3, c = plane % 3;
    const float* __restrict__ src = img + (size_t)plane * HW * HW;
    const int lx0 = bx * 32, ly0 = by * 32;   // low-res tile origin (128-space)

    for (int idx = tid; idx < 34 * 34; idx += 256) {
        const int r = idx / 34, col = idx % 34;
        const int ly = min(max(ly0 - 1 + r,   0), 127);
        const int lx = min(max(lx0 - 1 + col, 0), 127);
        const float* p = src + (size_t)(ly * 4) * HW + lx * 4;
        float s = 0.f;
        #pragma unroll
        for (int rr = 0; rr < 4; ++rr) {
            const float4 v = *(const float4*)(p + (size_t)rr * HW);
            s += v.x + v.y + v.z + v.w;
        }
        s_p[r * 35 + col] = s * (1.f / 16.f);
    }
    __syncthreads();

    const size_t outbase = (size_t)(b * 87 + c * 29 + 28) * HW * HW;
    for (int k = 0; k < 64; ++k) {
        const int pix = tid + k * 256;        // 0..16383, consecutive x -> coalesced
        const int ry = pix >> 7, rx = pix & 127;
        const int gy = ly0 * 4 + ry, gx = lx0 * 4 + rx;
        const float cy = (gy - 1.5f) * 0.25f;
        const float cx = (gx - 1.5f) * 0.25f;
        const int jy = (int)floorf(cy), jx = (int)floorf(cx);
        const float fy = cy - jy, fx = cx - jx;
        const int tyy = jy - (ly0 - 1);       // 0..32 (clamp folded into fill)
        const int txx = jx - (lx0 - 1);
        const float p00 = s_p[tyy * 35 + txx],       p01 = s_p[tyy * 35 + txx + 1];
        const float p10 = s_p[(tyy + 1) * 35 + txx], p11 = s_p[(tyy + 1) * 35 + txx + 1];
        const float v0 = p00 + fx * (p01 - p00);
        const float v1 = p10 + fx * (p11 - p10);
        out[outbase + (size_t)gy * HW + gx] = v0 + fy * (v1 - v0);
    }
}

extern "C" void kernel_launch(void* const* d_in, const int* in_sizes, int n_in,
                              void* d_out, int out_size, void* d_ws, size_t ws_size,
                              hipStream_t stream)
{
    const float* img = (const float*)d_in[0];
    const float* f0  = (const float*)d_in[1];
    const float* f1  = (const float*)d_in[2];
    const float* f2  = (const float*)d_in[3];
    float* out = (float*)d_out;

    dim3 block(256);
    dim3 grid(16, 16, 12);                    // 512/32, 512/32, B*3
    conv_kernel<11, 4,  0><<<grid, block, 0, stream>>>(img, f0, out);
    conv_kernel<15, 8,  4><<<grid, block, 0, stream>>>(img, f1, out);
    conv_kernel<19, 16, 12><<<grid, block, 0, stream>>>(img, f2, out);
    low_kernel<<<dim3(4, 4, 12), block, 0, stream>>>(img, out);
}

// Round 2
// 541.712 us; speedup vs baseline: 1.6722x; 1.6722x over previous
//
#include <hip/hip_runtime.h>
#include <hip/hip_bf16.h>

#define HW 512

typedef __attribute__((ext_vector_type(8))) short bf16x8;
typedef __attribute__((ext_vector_type(4))) float floatx4;

union BFrag { uint2 u2[2]; bf16x8 v; };

static __device__ inline ushort f2bf(float f) {
    __hip_bfloat16 h = __float2bfloat16(f);
    return *(ushort*)&h;
}

// ---------------------------------------------------------------------------
// Implicit-GEMM grouped directional conv on mfma_f32_16x16x32_bf16.
//   M = 16 = NDIR dirs x YPACK output rows (YPACK = 16/NDIR)
//   N = 16 pixels, strided by 4: px = gx0 + r + 4n, phase r = wave id (0..3)
//   K = im2col taps, chunked as (dyu row, 8-consecutive-dx octet), the dx
//       window shifted by -r inside the A fragment so B addresses are
//       phase-independent and 8B-aligned (ds_read_b64).
// A-fragment layout: A[m=lane&15][k=quad*8+j]; B[k=quad*8+j][n=lane&15];
// D: col=lane&15, row=quad*4+reg.  (per cdna_hip_programming.md §3, m89/m120)
// ---------------------------------------------------------------------------
template<int K, int NDIR, int SUB0, int YPACK, int OCTS, int NSTEP>
__global__ __launch_bounds__(256)
void mfma_conv(const float* __restrict__ img, const float* __restrict__ filt,
               float* __restrict__ out)
{
    constexpr int R       = K / 2;
    constexpr int TILE_W  = 64, TILE_H = 32;
    constexpr int NCHAIN  = TILE_H / YPACK;
    constexpr int ROWSP   = (4 * NSTEP - 1) / OCTS + 1;        // staged dyu rows
    constexpr int EXT_Y   = (TILE_H - YPACK) + ROWSP;          // staged image rows
    constexpr int EXT_X   = 4 * 15 + 8 * (OCTS - 1) + 8;       // max col read + 1
    constexpr int SPX     = (EXT_X + 7) & ~7;                  // row stride (mult of 8 elems)
    constexpr int P       = (OCTS == 3) ? 3 : 1;               // addr period in steps
    constexpr int GSTRIDE = (4 * P / OCTS) * SPX;              // elems per step-group

    __shared__ __align__(16) ushort s_img[EXT_Y * SPX];

    const int tid   = threadIdx.x;
    const int bx    = blockIdx.x, by = blockIdx.y, plane = blockIdx.z;
    const int bb    = plane / 3, cc = plane % 3;
    const float* __restrict__ src = img + (size_t)plane * HW * HW;
    const int gx0 = bx * TILE_W, gy0 = by * TILE_H;

    // ---- stage image tile as bf16 (zero-filled OOB; pad cols defined) ----
    constexpr int PAIRS = SPX / 2;
    for (int idx = tid; idx < EXT_Y * PAIRS; idx += 256) {
        const int row = idx / PAIRS;
        const int col = (idx - row * PAIRS) * 2;
        const int gy = gy0 - R + row;
        const int gx = gx0 - R + col;
        float v0 = 0.f, v1 = 0.f;
        if ((unsigned)gy < HW) {
            if ((unsigned)gx       < HW) v0 = src[gy * HW + gx];
            if ((unsigned)(gx + 1) < HW) v1 = src[gy * HW + gx + 1];
        }
        *(uint*)&s_img[row * SPX + col] = ((uint)f2bf(v1) << 16) | (uint)f2bf(v0);
    }

    // ---- build A fragments (filters, phase-shifted, zero-padded) ----
    const int lane = tid & 63;
    const int r    = tid >> 6;                 // wave id = pixel phase
    const int mn   = lane & 15;                // m for A, n for B/D
    const int q    = lane >> 4;                // quad
    const int dirm = mn & (NDIR - 1);
    const int yoffm = mn / NDIR;

    bf16x8 afrag[NSTEP];
    #pragma unroll
    for (int s = 0; s < NSTEP; ++s) {
        #pragma unroll
        for (int j = 0; j < 8; ++j) {
            const int c   = 4 * s + q;
            const int dyu = c / OCTS, o = c - dyu * OCTS;
            const int dy  = dyu - yoffm;
            const int dx  = 8 * o + j - r;
            float fv = 0.f;
            if (dy >= 0 && dy < K && dx >= 0 && dx < K)
                fv = filt[(dirm * K + dy) * K + dx];
            afrag[s][j] = (short)f2bf(fv);
        }
    }
    __syncthreads();

    // per-lane base offsets (elements) for s % P = 0..P-1, chain y = 0
    int base0[P];
    #pragma unroll
    for (int s0 = 0; s0 < P; ++s0) {
        const int c0   = 4 * s0 + q;
        const int dyu0 = c0 / OCTS, o0 = c0 - dyu0 * OCTS;
        base0[s0] = dyu0 * SPX + 8 * o0 + 4 * mn;   // 8B-aligned: SPX%8==0
    }

    const int px = gx0 + r + 4 * mn;

    for (int ch = 0; ch < NCHAIN; ++ch) {
        const int y = ch * YPACK;
        floatx4 acc = {0.f, 0.f, 0.f, 0.f};
        #pragma unroll
        for (int s = 0; s < NSTEP; ++s) {
            const int s0 = s % P, g = s / P;        // compile-time in unrolled loop
            const ushort* p = s_img + (base0[s0] + y * SPX + g * GSTRIDE);
            BFrag b;
            b.u2[0] = *(const uint2*)p;
            b.u2[1] = *(const uint2*)(p + 4);
            acc = __builtin_amdgcn_mfma_f32_16x16x32_bf16(afrag[s], b.v, acc, 0, 0, 0);
        }
        #pragma unroll
        for (int i = 0; i < 4; ++i) {
            const int mrow = q * 4 + i;
            const int dd = mrow & (NDIR - 1);
            const int yo = mrow / NDIR;
            const int Y  = gy0 + y + yo;
            out[((size_t)(bb * 87 + cc * 29 + SUB0 + dd) * HW + Y) * HW + px] = acc[i];
        }
    }
}

// ---------------------------------------------------------------------------
// Low channel: 4x4 avg-pool + 4x bilinear upsample (half-pixel, edge clamp).
// ---------------------------------------------------------------------------
__global__ __launch_bounds__(256)
void low_kernel(const float* __restrict__ img, float* __restrict__ out)
{
    __shared__ float s_p[34 * 35];
    const int tid   = threadIdx.x;
    const int bx    = blockIdx.x, by = blockIdx.y;
    const int plane = blockIdx.z;
    const int b     = plane / 3, c = plane % 3;
    const float* __restrict__ src = img + (size_t)plane * HW * HW;
    const int lx0 = bx * 32, ly0 = by * 32;

    for (int idx = tid; idx < 34 * 34; idx += 256) {
        const int r = idx / 34, col = idx % 34;
        const int ly = min(max(ly0 - 1 + r,   0), 127);
        const int lx = min(max(lx0 - 1 + col, 0), 127);
        const float* p = src + (size_t)(ly * 4) * HW + lx * 4;
        float s = 0.f;
        #pragma unroll
        for (int rr = 0; rr < 4; ++rr) {
            const float4 v = *(const float4*)(p + (size_t)rr * HW);
            s += v.x + v.y + v.z + v.w;
        }
        s_p[r * 35 + col] = s * (1.f / 16.f);
    }
    __syncthreads();

    const size_t outbase = (size_t)(b * 87 + c * 29 + 28) * HW * HW;
    for (int k = 0; k < 64; ++k) {
        const int pix = tid + k * 256;
        const int ry = pix >> 7, rx = pix & 127;
        const int gy = ly0 * 4 + ry, gx = lx0 * 4 + rx;
        const float cy = (gy - 1.5f) * 0.25f;
        const float cx = (gx - 1.5f) * 0.25f;
        const int jy = (int)floorf(cy), jx = (int)floorf(cx);
        const float fy = cy - jy, fx = cx - jx;
        const int tyy = jy - (ly0 - 1);
        const int txx = jx - (lx0 - 1);
        const float p00 = s_p[tyy * 35 + txx],       p01 = s_p[tyy * 35 + txx + 1];
        const float p10 = s_p[(tyy + 1) * 35 + txx], p11 = s_p[(tyy + 1) * 35 + txx + 1];
        const float v0 = p00 + fx * (p01 - p00);
        const float v1 = p10 + fx * (p11 - p10);
        out[outbase + (size_t)gy * HW + gx] = v0 + fy * (v1 - v0);
    }
}

extern "C" void kernel_launch(void* const* d_in, const int* in_sizes, int n_in,
                              void* d_out, int out_size, void* d_ws, size_t ws_size,
                              hipStream_t stream)
{
    const float* img = (const float*)d_in[0];
    const float* f0  = (const float*)d_in[1];
    const float* f1  = (const float*)d_in[2];
    const float* f2  = (const float*)d_in[3];
    float* out = (float*)d_out;

    dim3 block(256);
    dim3 grid(HW / 64, HW / 32, 12);             // 8 x 16 x 12

    // <K, NDIR, SUB0, YPACK, OCTS, NSTEP>
    mfma_conv<11,  4,  0, 4, 2,  7><<<grid, block, 0, stream>>>(img, f0, out);
    mfma_conv<15,  8,  4, 2, 3, 12><<<grid, block, 0, stream>>>(img, f1, out);
    mfma_conv<19, 16, 12, 1, 3, 15><<<grid, block, 0, stream>>>(img, f2, out);
    low_kernel<<<dim3(4, 4, 12), block, 0, stream>>>(img, out);
}